// Round 9
// baseline (114.472 us; speedup 1.0000x reference)
//
#include <hip/hip_runtime.h>
#include <hip/hip_bf16.h>
#include <stdint.h>
#include <math.h>

// MMD: N=8192 rows (4096 source + 4096 target), D=256, fp32 in, scalar fp32 out.
// result = (1/4096^2) * sum_ij s_i s_j ksum(L2_ij),  s_i = +1 (i<4096) else -1
// ksum = w + w^2 + w^4 + w^8 + w^16,  w = exp(-L2/(16 bw0))
// bw0 = [2N*sum(sq) - 2*sum_d colsum_d^2] / (N^2-N) / 4  (analytic sum(L2))
// R1: same-address fp64 atomics catastrophic. R2: XOR swizzle vs LDS
// conflicts. R3: fp8 MX K=128. R5 FAILED: per-block agent fences -> 84us.
// R6 (98us): split-K LDS, 4 blk/CU. R7 FAILED: pair-tile 2 blk/CU -> 103us.
// R8 (94.5us): kred folded into kconv atomics + kgemm prologue; diag last.
// R9: kgemm by-elimination is ~35us vs ~15us of actual pipe work — the gap
//     is the vmcnt(0)+s_barrier drain after every staging phase (the m97
//     structural stall). Fix: NO LDS staging at all. D=256 fp8 means a
//     lane's fragment = 32 contiguous bytes — load straight from global
//     (L2-resident, 2MB X8 fits every XCD L2; q-group spans consume full
//     128B lines). Zero barriers in the main path; waves run async.

#define NTOT 8192
#define DDIM 256
#define TILE 128
#define NBLK 2080   // 2016 strict-upper off-diag + 64 diagonal (last)

typedef int i32x8 __attribute__((ext_vector_type(8)));
typedef int i32x4 __attribute__((ext_vector_type(4)));
typedef float f32x4 __attribute__((ext_vector_type(4)));
typedef float f32x2 __attribute__((ext_vector_type(2)));

// ---- fp32 -> fp8(e4m3) convert + per-row sq + f32-atomic column/sq sums ----
__global__ __launch_bounds__(256) void kconv(const float* __restrict__ src,
                                             const float* __restrict__ tgt,
                                             unsigned char* __restrict__ X8,
                                             float* __restrict__ sq,
                                             float* __restrict__ colsum,   // [256]
                                             float* __restrict__ ssqacc) {
  int b = blockIdx.x;           // 256 blocks, 32 rows each
  int t = threadIdx.x;
  int lane = t & 63, wave = t >> 6;
  float cp0 = 0.f, cp1 = 0.f, cp2 = 0.f, cp3 = 0.f;
  float sqp = 0.f;

  #pragma unroll
  for (int it = 0; it < 8; ++it) {
    int row = b * 32 + it * 4 + wave;
    const float* base = (row < 4096) ? (src + (size_t)row * DDIM)
                                     : (tgt + (size_t)(row - 4096) * DDIM);
    float4 v = ((const float4*)base)[lane];
    int p = __builtin_amdgcn_cvt_pk_fp8_f32(v.x, v.y, 0, false);
    p = __builtin_amdgcn_cvt_pk_fp8_f32(v.z, v.w, p, true);
    ((int*)(X8 + (size_t)row * DDIM))[lane] = p;
    float f0 = __builtin_amdgcn_cvt_f32_fp8(p, 0);
    float f1 = __builtin_amdgcn_cvt_f32_fp8(p, 1);
    float f2 = __builtin_amdgcn_cvt_f32_fp8(p, 2);
    float f3 = __builtin_amdgcn_cvt_f32_fp8(p, 3);
    cp0 += f0; cp1 += f1; cp2 += f2; cp3 += f3;
    float s = f0 * f0 + f1 * f1 + f2 * f2 + f3 * f3;
    #pragma unroll
    for (int off = 32; off; off >>= 1) s += __shfl_down(s, off);
    if (lane == 0) { sq[row] = s; sqp += s; }
  }

  __shared__ float cred[4][256];
  __shared__ float sred[4];
  ((float4*)&cred[wave][lane * 4])[0] = make_float4(cp0, cp1, cp2, cp3);
  if (lane == 0) sred[wave] = sqp;
  __syncthreads();
  float csum = cred[0][t] + cred[1][t] + cred[2][t] + cred[3][t];
  atomicAdd(&colsum[t], csum);   // 256 distinct addresses: native f32, no hot-spot
  if (t == 0) atomicAdd(ssqacc, sred[0] + sred[1] + sred[2] + sred[3]);
}

// ---- main: triangular Gram, MX-fp8 K=128, fragments direct from global ----
// b < 2016: strict-upper off-diag tile; b >= 2016: diagonal tile (last)
__global__ __launch_bounds__(256, 4) void kgemm(const unsigned char* __restrict__ X8,
                                                const float* __restrict__ sq,
                                                const float* __restrict__ colsum,
                                                const float* __restrict__ ssqacc,
                                                double* __restrict__ Spart) {
  int b = blockIdx.x;
  int tr, tc;
  if (b < 2016) {  // strict upper: offset(tr) = tr*(127-tr)/2
    tr = (int)((127.0 - sqrt(127.0 * 127.0 - 8.0 * (double)b)) * 0.5);
    while (tr > 0 && tr * (127 - tr) / 2 > b) --tr;
    while ((tr + 1) * (126 - tr) / 2 <= b) ++tr;
    tc = tr + 1 + (b - tr * (127 - tr) / 2);
  } else {
    tr = tc = b - 2016;
  }
  bool diag = (tr == tc);

  __shared__ double red[4];

  int t = threadIdx.x;
  int wave = t >> 6, lane = t & 63;
  int mrow = lane & 15, q = lane >> 4;
  int wr = (wave & 1) * 64, wc = (wave >> 1) * 64;
  const int sone = 0x7F7F7F7F;  // e8m0 scale = 1.0

  // lane's base row pointers: fragment = 32 contiguous bytes at q*32 (+ki*128)
  const unsigned char* Abase = X8 + ((size_t)(tr * TILE + wr + mrow)) * DDIM + q * 32;
  const unsigned char* Bbase = X8 + ((size_t)(tc * TILE + wc + mrow)) * DDIM + q * 32;

  // ---- wave-redundant bw0 (L2-resident scalars; overlaps with frag loads) ----
  float4 cv = ((const float4*)colsum)[lane];
  float scp = cv.x * cv.x + cv.y * cv.y + cv.z * cv.z + cv.w * cv.w;
  #pragma unroll
  for (int off = 32; off; off >>= 1) scp += __shfl_down(scp, off);
  scp = __shfl(scp, 0);
  float ssq = *ssqacc;
  double sumL2 = 2.0 * 8192.0 * (double)ssq - 2.0 * (double)scp;
  double bw0 = sumL2 / (8192.0 * 8192.0 - 8192.0) / 4.0;
  float kk = (float)(-1.44269504088896 / (16.0 * bw0));  // cs * log2(e)

  f32x4 acc[4][4];
  #pragma unroll
  for (int i = 0; i < 4; ++i)
    #pragma unroll
    for (int j = 0; j < 4; ++j) acc[i][j] = (f32x4){0.f, 0.f, 0.f, 0.f};

  // ---- two K-halves; all loads straight from global (L2), no barriers ----
  #pragma unroll
  for (int ki = 0; ki < 2; ++ki) {
    i32x8 af[4], bf[4];
    #pragma unroll
    for (int f = 0; f < 4; ++f) {   // row-block f: +16 rows = +4096 B
      const unsigned char* pa = Abase + (size_t)f * 16 * DDIM + ki * 128;
      const unsigned char* pb = Bbase + (size_t)f * 16 * DDIM + ki * 128;
      *(i32x4*)&af[f]       = *(const i32x4*)(pa);
      *((i32x4*)&af[f] + 1) = *(const i32x4*)(pa + 16);
      *(i32x4*)&bf[f]       = *(const i32x4*)(pb);
      *((i32x4*)&bf[f] + 1) = *(const i32x4*)(pb + 16);
    }
    #pragma unroll
    for (int fr = 0; fr < 4; ++fr)
      #pragma unroll
      for (int fc = 0; fc < 4; ++fc)
        acc[fr][fc] = __builtin_amdgcn_mfma_scale_f32_16x16x128_f8f6f4(
            af[fr], bf[fc], acc[fr][fc], 0, 0, 0, sone, 0, sone);
  }

  // epilogue: x = -2k*dot + sr + sc; w = exp2(x); ksum = w+w2+w4+w8+w16.
  // sq read from global: sr loads broadcast within q-group (L1), sc coalesced.
  // C/D layout col=lane&15, row=(lane>>4)*4+reg [m89/m91; dtype-indep]
  float a2s = -2.f * kk;
  f32x2 a2 = {a2s, a2s};
  f32x2 sum2 = {0.f, 0.f};
  int rq = q * 4, cl = mrow;
  const float* sqR = sq + tr * TILE;
  const float* sqC = sq + tc * TILE;
  #pragma unroll
  for (int fr = 0; fr < 4; ++fr) {
    int rbase = wr + 16 * fr + rq;
    float4 srv = *(const float4*)&sqR[rbase];   // 4 row-sq, broadcast in q-group
    f32x2 sr01 = {kk * srv.x, kk * srv.y};
    f32x2 sr23 = {kk * srv.z, kk * srv.w};
    #pragma unroll
    for (int fc = 0; fc < 4; ++fc) {
      float sc = kk * sqC[wc + 16 * fc + cl];
      f32x2 scv = {sc, sc};
      f32x2 d01 = {acc[fr][fc][0], acc[fr][fc][1]};
      f32x2 d23 = {acc[fr][fc][2], acc[fr][fc][3]};
      f32x2 x01 = a2 * d01 + (sr01 + scv);
      f32x2 x23 = a2 * d23 + (sr23 + scv);
      f32x2 w01 = {__builtin_amdgcn_exp2f(x01.x), __builtin_amdgcn_exp2f(x01.y)};
      f32x2 w23 = {__builtin_amdgcn_exp2f(x23.x), __builtin_amdgcn_exp2f(x23.y)};
      f32x2 p01 = w01 * w01, p23 = w23 * w23;           // w^2
      f32x2 s01 = w01 + p01, s23 = w23 + p23;
      p01 = p01 * p01; p23 = p23 * p23;                 // w^4
      s01 = s01 + p01; s23 = s23 + p23;
      p01 = p01 * p01; p23 = p23 * p23;                 // w^8
      s01 = s01 + p01; s23 = s23 + p23;
      p01 = p01 * p01; p23 = p23 * p23;                 // w^16
      s01 = s01 + p01; s23 = s23 + p23;
      sum2 = sum2 + (s01 + s23);
    }
  }
  float lsum = sum2.x + sum2.y;

  double wt = diag ? 1.0 : 2.0;
  if ((tr < 32) != (tc < 32)) wt = -wt;  // s_i*s_j uniform per 128-tile
  double ds = (double)lsum * wt;
  #pragma unroll
  for (int off = 32; off; off >>= 1) ds += __shfl_down(ds, off);
  if (lane == 0) red[wave] = ds;
  __syncthreads();                       // the only barrier in this kernel
  if (t == 0) Spart[b] = red[0] + red[1] + red[2] + red[3];
}

// ---- final reduce of 2080 per-block partials ----
__global__ __launch_bounds__(256) void kfin(const double* __restrict__ Spart,
                                            float* __restrict__ out) {
  int t = threadIdx.x;
  double s = 0.0;
  #pragma unroll
  for (int i = 0; i < 9; ++i) {
    int idx = t + i * 256;
    if (idx < NBLK) s += Spart[idx];
  }
  __shared__ double red[256];
  red[t] = s;
  __syncthreads();
  for (int off = 128; off; off >>= 1) {
    if (t < off) red[t] += red[t + off];
    __syncthreads();
  }
  if (t == 0) out[0] = (float)(red[0] / (4096.0 * 4096.0));
}

extern "C" void kernel_launch(void* const* d_in, const int* in_sizes, int n_in,
                              void* d_out, int out_size, void* d_ws, size_t ws_size,
                              hipStream_t stream) {
  const float* src = (const float*)d_in[0];
  const float* tgt = (const float*)d_in[1];
  char* ws = (char*)d_ws;
  unsigned char* X8 = (unsigned char*)ws;             // 8192*256 = 2 MiB
  float* sq      = (float*)(ws + 2097152);            // 32 KiB
  float* colsum  = (float*)(ws + 2129920);            // 256 f + 1 f (ssq)
  float* ssqacc  = colsum + 256;
  double* Spart  = (double*)(ws + 2131968);           // 16.25 KiB
  float* out = (float*)d_out;

  hipMemsetAsync((void*)colsum, 0, 1040, stream);     // zero atomic targets
  hipLaunchKernelGGL(kconv, dim3(256), dim3(256), 0, stream,
                     src, tgt, X8, sq, colsum, ssqacc);
  hipLaunchKernelGGL(kgemm, dim3(NBLK), dim3(256), 0, stream,
                     X8, sq, colsum, ssqacc, Spart);
  hipLaunchKernelGGL(kfin, dim3(1), dim3(256), 0, stream, Spart, out);
}

// Round 10
// 99.438 us; speedup vs baseline: 1.1512x; 1.1512x over previous
//
#include <hip/hip_runtime.h>
#include <hip/hip_bf16.h>
#include <stdint.h>
#include <math.h>

// MMD: N=8192 rows (4096 source + 4096 target), D=256, fp32 in, scalar fp32 out.
// result = (1/4096^2) * sum_ij s_i s_j ksum(L2_ij),  s_i = +1 (i<4096) else -1
// ksum = w + w^2 + w^4 + w^8 + w^16,  w = exp(-L2/(16 bw0))
// bw0 = [2N*sum(sq) - 2*sum_d colsum_d^2] / (N^2-N) / 4  (analytic sum(L2))
// R1: same-address fp64 atomics catastrophic. R2: XOR swizzle vs LDS
// conflicts. R3: fp8 MX K=128. R5 FAILED: per-block agent fences -> 84us.
// R6 (98us): split-K LDS, 4 blk/CU. R7 FAILED: pair-tile 2 blk/CU -> 103us.
// R8 (94.5us, BEST): kconv atomics replace kred; bw0 in kgemm prologue.
// R9 FAILED (114.5us): no-LDS direct-global fragments -> latency-bound on
//     scattered 32B/256B-stride L2 gathers (MfmaUtil 6.8%). The DMA+barrier
//     staging pays for itself via line-coalescing. R8 structure is the
//     plateau at HIP level (matches m99-m141: vmcnt tweaks neutral).
// R10: R8 verbatim + kconv 512 blocks (was 256; 1 blk/CU -> 2 for latency).

#define NTOT 8192
#define DDIM 256
#define TILE 128
#define NBLK 2080   // 2016 strict-upper off-diag + 64 diagonal (last)

typedef int i32x8 __attribute__((ext_vector_type(8)));
typedef int i32x4 __attribute__((ext_vector_type(4)));
typedef float f32x4 __attribute__((ext_vector_type(4)));
typedef float f32x2 __attribute__((ext_vector_type(2)));

__device__ __forceinline__ void gl_lds16(const void* g, void* l) {
  __builtin_amdgcn_global_load_lds(
      (const __attribute__((address_space(1))) void*)g,
      (__attribute__((address_space(3))) void*)l, 16, 0, 0);
}

// ---- fp32 -> fp8(e4m3) convert + per-row sq + f32-atomic column/sq sums ----
__global__ __launch_bounds__(256) void kconv(const float* __restrict__ src,
                                             const float* __restrict__ tgt,
                                             unsigned char* __restrict__ X8,
                                             float* __restrict__ sq,
                                             float* __restrict__ colsum,   // [256]
                                             float* __restrict__ ssqacc) {
  int b = blockIdx.x;           // 512 blocks, 16 rows each
  int t = threadIdx.x;
  int lane = t & 63, wave = t >> 6;
  float cp0 = 0.f, cp1 = 0.f, cp2 = 0.f, cp3 = 0.f;
  float sqp = 0.f;

  #pragma unroll
  for (int it = 0; it < 4; ++it) {
    int row = b * 16 + it * 4 + wave;
    const float* base = (row < 4096) ? (src + (size_t)row * DDIM)
                                     : (tgt + (size_t)(row - 4096) * DDIM);
    float4 v = ((const float4*)base)[lane];
    int p = __builtin_amdgcn_cvt_pk_fp8_f32(v.x, v.y, 0, false);
    p = __builtin_amdgcn_cvt_pk_fp8_f32(v.z, v.w, p, true);
    ((int*)(X8 + (size_t)row * DDIM))[lane] = p;
    float f0 = __builtin_amdgcn_cvt_f32_fp8(p, 0);
    float f1 = __builtin_amdgcn_cvt_f32_fp8(p, 1);
    float f2 = __builtin_amdgcn_cvt_f32_fp8(p, 2);
    float f3 = __builtin_amdgcn_cvt_f32_fp8(p, 3);
    cp0 += f0; cp1 += f1; cp2 += f2; cp3 += f3;
    float s = f0 * f0 + f1 * f1 + f2 * f2 + f3 * f3;
    #pragma unroll
    for (int off = 32; off; off >>= 1) s += __shfl_down(s, off);
    if (lane == 0) { sq[row] = s; sqp += s; }
  }

  __shared__ float cred[4][256];
  __shared__ float sred[4];
  ((float4*)&cred[wave][lane * 4])[0] = make_float4(cp0, cp1, cp2, cp3);
  if (lane == 0) sred[wave] = sqp;
  __syncthreads();
  float csum = cred[0][t] + cred[1][t] + cred[2][t] + cred[3][t];
  atomicAdd(&colsum[t], csum);   // 256 distinct addresses: native f32, no hot-spot
  if (t == 0) atomicAdd(ssqacc, sred[0] + sred[1] + sred[2] + sred[3]);
}

// ---- main: triangular Gram, MX-fp8 K=128 x2 halves, 34KB LDS, 4 blk/CU ----
// b < 2016: strict-upper off-diag tile; b >= 2016: diagonal tile (light, last)
__global__ __launch_bounds__(256, 4) void kgemm(const unsigned char* __restrict__ X8,
                                                const float* __restrict__ sq,
                                                const float* __restrict__ colsum,
                                                const float* __restrict__ ssqacc,
                                                double* __restrict__ Spart) {
  int b = blockIdx.x;
  int tr, tc;
  if (b < 2016) {  // strict upper: offset(tr) = tr*(127-tr)/2
    tr = (int)((127.0 - sqrt(127.0 * 127.0 - 8.0 * (double)b)) * 0.5);
    while (tr > 0 && tr * (127 - tr) / 2 > b) --tr;
    while ((tr + 1) * (126 - tr) / 2 <= b) ++tr;
    tc = tr + 1 + (b - tr * (127 - tr) / 2);
  } else {
    tr = tc = b - 2016;
  }
  bool diag = (tr == tc);

  __shared__ alignas(16) unsigned char Ash[TILE * 128];  // 16 KB (one K-half)
  __shared__ alignas(16) unsigned char Bsh[TILE * 128];  // 16 KB
  __shared__ float sqR2[TILE], sqC2[TILE];
  __shared__ double red[4];

  int t = threadIdx.x;
  int wave = t >> 6, lane = t & 63;
  int mrow = lane & 15, q = lane >> 4;
  int wr = (wave & 1) * 64, wc = (wave >> 1) * 64;
  const int sone = 0x7F7F7F7F;  // e8m0 scale = 1.0

  const unsigned char* Ag = X8 + (size_t)tr * TILE * DDIM;
  const unsigned char* Bg = X8 + (size_t)tc * TILE * DDIM;

  // ---- issue half-0 staging FIRST (bw0 compute hides behind it) ----
  #pragma unroll
  for (int cc = 0; cc < 4; ++cc) {
    int c = t + cc * 256;
    int row = c >> 3, kcs = c & 7;
    int kc = kcs ^ (row & 7);
    gl_lds16(Ag + (size_t)row * DDIM + kc * 16, Ash + c * 16);
  }
  if (!diag) {
    #pragma unroll
    for (int cc = 0; cc < 4; ++cc) {
      int c = t + cc * 256;
      int row = c >> 3, kcs = c & 7;
      int kc = kcs ^ (row & 7);
      gl_lds16(Bg + (size_t)row * DDIM + kc * 16, Bsh + c * 16);
    }
  }

  // ---- wave-redundant bw0: colsum^2 sum + ssq, 6 shuffle rounds, no LDS ----
  float4 cv = ((const float4*)colsum)[lane];
  float scp = cv.x * cv.x + cv.y * cv.y + cv.z * cv.z + cv.w * cv.w;
  #pragma unroll
  for (int off = 32; off; off >>= 1) scp += __shfl_down(scp, off);
  scp = __shfl(scp, 0);                 // Σ colsum_d^2 (all lanes)
  float ssq = *ssqacc;
  double sumL2 = 2.0 * 8192.0 * (double)ssq - 2.0 * (double)scp;
  double bw0 = sumL2 / (8192.0 * 8192.0 - 8192.0) / 4.0;
  float kk = (float)(-1.44269504088896 / (16.0 * bw0));  // cs * log2(e)

  if (t < 128) sqR2[t] = kk * sq[tr * TILE + t];
  else         sqC2[t - 128] = kk * sq[tc * TILE + (t - 128)];

  f32x4 acc[4][4];
  #pragma unroll
  for (int i = 0; i < 4; ++i)
    #pragma unroll
    for (int j = 0; j < 4; ++j) acc[i][j] = (f32x4){0.f, 0.f, 0.f, 0.f};

  // ---- two K-halves of 128 bytes, single-buffered ----
  for (int s = 0; s < 2; ++s) {
    if (s) {  // restage half 1
      __syncthreads();  // all reads of half 0 complete
      #pragma unroll
      for (int cc = 0; cc < 4; ++cc) {
        int c = t + cc * 256;
        int row = c >> 3, kcs = c & 7;
        int kc = kcs ^ (row & 7);
        gl_lds16(Ag + (size_t)row * DDIM + 128 + kc * 16, Ash + c * 16);
      }
      if (!diag) {
        #pragma unroll
        for (int cc = 0; cc < 4; ++cc) {
          int c = t + cc * 256;
          int row = c >> 3, kcs = c & 7;
          int kc = kcs ^ (row & 7);
          gl_lds16(Bg + (size_t)row * DDIM + 128 + kc * 16, Bsh + c * 16);
        }
      }
    }
    __syncthreads();  // staging done (s=0: also sqR2/sqC2 visible)

    const unsigned char* Bs = diag ? Ash : Bsh;
    int kc0 = q * 2;
    i32x8 af[4], bf[4];
    #pragma unroll
    for (int f = 0; f < 4; ++f) {
      int rowA = wr + 16 * f + mrow;
      int rowB = wc + 16 * f + mrow;
      int sw = mrow & 7;
      *(i32x4*)&af[f]       = *(const i32x4*)&Ash[rowA * 128 + (kc0 ^ sw) * 16];
      *((i32x4*)&af[f] + 1) = *(const i32x4*)&Ash[rowA * 128 + ((kc0 + 1) ^ sw) * 16];
      *(i32x4*)&bf[f]       = *(const i32x4*)&Bs[rowB * 128 + (kc0 ^ sw) * 16];
      *((i32x4*)&bf[f] + 1) = *(const i32x4*)&Bs[rowB * 128 + ((kc0 + 1) ^ sw) * 16];
    }
    #pragma unroll
    for (int fr = 0; fr < 4; ++fr)
      #pragma unroll
      for (int fc = 0; fc < 4; ++fc)
        acc[fr][fc] = __builtin_amdgcn_mfma_scale_f32_16x16x128_f8f6f4(
            af[fr], bf[fc], acc[fr][fc], 0, 0, 0, sone, 0, sone);
  }

  // epilogue: x = -2k*dot + sr + sc; w = exp2(x); ksum = w+w2+w4+w8+w16.
  // packed f32x2; no clamp (only diag ~0, err negligible).
  // C/D layout col=lane&15, row=(lane>>4)*4+reg [m89/m91; dtype-indep]
  float a2s = -2.f * kk;
  f32x2 a2 = {a2s, a2s};
  f32x2 sum2 = {0.f, 0.f};
  int rq = q * 4, cl = mrow;
  #pragma unroll
  for (int fr = 0; fr < 4; ++fr) {
    int rbase = wr + 16 * fr + rq;
    f32x2 sr01 = {sqR2[rbase + 0], sqR2[rbase + 1]};
    f32x2 sr23 = {sqR2[rbase + 2], sqR2[rbase + 3]};
    #pragma unroll
    for (int fc = 0; fc < 4; ++fc) {
      float sc = sqC2[wc + 16 * fc + cl];
      f32x2 scv = {sc, sc};
      f32x2 d01 = {acc[fr][fc][0], acc[fr][fc][1]};
      f32x2 d23 = {acc[fr][fc][2], acc[fr][fc][3]};
      f32x2 x01 = a2 * d01 + (sr01 + scv);
      f32x2 x23 = a2 * d23 + (sr23 + scv);
      f32x2 w01 = {__builtin_amdgcn_exp2f(x01.x), __builtin_amdgcn_exp2f(x01.y)};
      f32x2 w23 = {__builtin_amdgcn_exp2f(x23.x), __builtin_amdgcn_exp2f(x23.y)};
      f32x2 p01 = w01 * w01, p23 = w23 * w23;           // w^2
      f32x2 s01 = w01 + p01, s23 = w23 + p23;
      p01 = p01 * p01; p23 = p23 * p23;                 // w^4
      s01 = s01 + p01; s23 = s23 + p23;
      p01 = p01 * p01; p23 = p23 * p23;                 // w^8
      s01 = s01 + p01; s23 = s23 + p23;
      p01 = p01 * p01; p23 = p23 * p23;                 // w^16
      s01 = s01 + p01; s23 = s23 + p23;
      sum2 = sum2 + (s01 + s23);
    }
  }
  float lsum = sum2.x + sum2.y;

  double wt = diag ? 1.0 : 2.0;
  if ((tr < 32) != (tc < 32)) wt = -wt;  // s_i*s_j uniform per 128-tile
  double ds = (double)lsum * wt;
  #pragma unroll
  for (int off = 32; off; off >>= 1) ds += __shfl_down(ds, off);
  if (lane == 0) red[wave] = ds;
  __syncthreads();
  if (t == 0) Spart[b] = red[0] + red[1] + red[2] + red[3];
}

// ---- final reduce of 2080 per-block partials ----
__global__ __launch_bounds__(256) void kfin(const double* __restrict__ Spart,
                                            float* __restrict__ out) {
  int t = threadIdx.x;
  double s = 0.0;
  #pragma unroll
  for (int i = 0; i < 9; ++i) {
    int idx = t + i * 256;
    if (idx < NBLK) s += Spart[idx];
  }
  __shared__ double red[256];
  red[t] = s;
  __syncthreads();
  for (int off = 128; off; off >>= 1) {
    if (t < off) red[t] += red[t + off];
    __syncthreads();
  }
  if (t == 0) out[0] = (float)(red[0] / (4096.0 * 4096.0));
}

extern "C" void kernel_launch(void* const* d_in, const int* in_sizes, int n_in,
                              void* d_out, int out_size, void* d_ws, size_t ws_size,
                              hipStream_t stream) {
  const float* src = (const float*)d_in[0];
  const float* tgt = (const float*)d_in[1];
  char* ws = (char*)d_ws;
  unsigned char* X8 = (unsigned char*)ws;             // 8192*256 = 2 MiB
  float* sq      = (float*)(ws + 2097152);            // 32 KiB
  float* colsum  = (float*)(ws + 2129920);            // 256 f + 1 f (ssq)
  float* ssqacc  = colsum + 256;
  double* Spart  = (double*)(ws + 2131968);           // 16.25 KiB
  float* out = (float*)d_out;

  hipMemsetAsync((void*)colsum, 0, 1040, stream);     // zero atomic targets
  hipLaunchKernelGGL(kconv, dim3(512), dim3(256), 0, stream,
                     src, tgt, X8, sq, colsum, ssqacc);
  hipLaunchKernelGGL(kgemm, dim3(NBLK), dim3(256), 0, stream,
                     X8, sq, colsum, ssqacc, Spart);
  hipLaunchKernelGGL(kfin, dim3(1), dim3(256), 0, stream, Spart, out);
}

// Round 11
// 94.776 us; speedup vs baseline: 1.2078x; 1.0492x over previous
//
#include <hip/hip_runtime.h>
#include <hip/hip_bf16.h>
#include <stdint.h>
#include <math.h>

// MMD: N=8192 rows (4096 source + 4096 target), D=256, fp32 in, scalar fp32 out.
// result = (1/4096^2) * sum_ij s_i s_j ksum(L2_ij),  s_i = +1 (i<4096) else -1
// ksum = w + w^2 + w^4 + w^8 + w^16,  w = exp(-L2/(16 bw0))
// bw0 = [2N*sum(sq) - 2*sum_d colsum_d^2] / (N^2-N) / 4  (analytic sum(L2))
// Session ledger:
// R1: same-address fp64 atomics catastrophic (102us kconv). R2: XOR swizzle
// kills LDS conflicts. R3: MX-fp8 K=128 MFMA. R5 FAILED: per-block agent
// fences = L2 wb/inv per block -> 84us kgemm. R6: split-K LDS, 4 blk/CU,
// packed exp2 epilogue -> 98us. R7 FAILED: pair-tile 2 blk/CU -> 103us
// (occupancy > barriers > staged bytes). R8 BEST (94.5us): kred folded into
// kconv distinct-address f32 atomics + wave-redundant bw0 in kgemm prologue,
// diagonal tiles last. R9 FAILED (114.5us): no-LDS direct-global fragments
// latency-bound on scattered gathers — DMA staging pays for itself via line
// coalescing. R10: kconv 512 blocks neutral-to-negative. This is R8 verbatim.
// Remaining gap is (a) ~43us harness ws-poison fill (fixed), (b) kgemm's
// vmcnt(0)+barrier drain — the m97-class structural stall, not fixable at
// HIP source level (learn_hip m99-m141), (c) graph-node gaps.

#define NTOT 8192
#define DDIM 256
#define TILE 128
#define NBLK 2080   // 2016 strict-upper off-diag + 64 diagonal (last)

typedef int i32x8 __attribute__((ext_vector_type(8)));
typedef int i32x4 __attribute__((ext_vector_type(4)));
typedef float f32x4 __attribute__((ext_vector_type(4)));
typedef float f32x2 __attribute__((ext_vector_type(2)));

__device__ __forceinline__ void gl_lds16(const void* g, void* l) {
  __builtin_amdgcn_global_load_lds(
      (const __attribute__((address_space(1))) void*)g,
      (__attribute__((address_space(3))) void*)l, 16, 0, 0);
}

// ---- fp32 -> fp8(e4m3) convert + per-row sq + f32-atomic column/sq sums ----
__global__ __launch_bounds__(256) void kconv(const float* __restrict__ src,
                                             const float* __restrict__ tgt,
                                             unsigned char* __restrict__ X8,
                                             float* __restrict__ sq,
                                             float* __restrict__ colsum,   // [256]
                                             float* __restrict__ ssqacc) {
  int b = blockIdx.x;           // 256 blocks, 32 rows each
  int t = threadIdx.x;
  int lane = t & 63, wave = t >> 6;
  float cp0 = 0.f, cp1 = 0.f, cp2 = 0.f, cp3 = 0.f;
  float sqp = 0.f;

  #pragma unroll
  for (int it = 0; it < 8; ++it) {
    int row = b * 32 + it * 4 + wave;
    const float* base = (row < 4096) ? (src + (size_t)row * DDIM)
                                     : (tgt + (size_t)(row - 4096) * DDIM);
    float4 v = ((const float4*)base)[lane];
    int p = __builtin_amdgcn_cvt_pk_fp8_f32(v.x, v.y, 0, false);
    p = __builtin_amdgcn_cvt_pk_fp8_f32(v.z, v.w, p, true);
    ((int*)(X8 + (size_t)row * DDIM))[lane] = p;
    float f0 = __builtin_amdgcn_cvt_f32_fp8(p, 0);
    float f1 = __builtin_amdgcn_cvt_f32_fp8(p, 1);
    float f2 = __builtin_amdgcn_cvt_f32_fp8(p, 2);
    float f3 = __builtin_amdgcn_cvt_f32_fp8(p, 3);
    cp0 += f0; cp1 += f1; cp2 += f2; cp3 += f3;
    float s = f0 * f0 + f1 * f1 + f2 * f2 + f3 * f3;
    #pragma unroll
    for (int off = 32; off; off >>= 1) s += __shfl_down(s, off);
    if (lane == 0) { sq[row] = s; sqp += s; }
  }

  __shared__ float cred[4][256];
  __shared__ float sred[4];
  ((float4*)&cred[wave][lane * 4])[0] = make_float4(cp0, cp1, cp2, cp3);
  if (lane == 0) sred[wave] = sqp;
  __syncthreads();
  float csum = cred[0][t] + cred[1][t] + cred[2][t] + cred[3][t];
  atomicAdd(&colsum[t], csum);   // 256 distinct addresses: native f32, no hot-spot
  if (t == 0) atomicAdd(ssqacc, sred[0] + sred[1] + sred[2] + sred[3]);
}

// ---- main: triangular Gram, MX-fp8 K=128 x2 halves, 34KB LDS, 4 blk/CU ----
// b < 2016: strict-upper off-diag tile; b >= 2016: diagonal tile (light, last)
__global__ __launch_bounds__(256, 4) void kgemm(const unsigned char* __restrict__ X8,
                                                const float* __restrict__ sq,
                                                const float* __restrict__ colsum,
                                                const float* __restrict__ ssqacc,
                                                double* __restrict__ Spart) {
  int b = blockIdx.x;
  int tr, tc;
  if (b < 2016) {  // strict upper: offset(tr) = tr*(127-tr)/2
    tr = (int)((127.0 - sqrt(127.0 * 127.0 - 8.0 * (double)b)) * 0.5);
    while (tr > 0 && tr * (127 - tr) / 2 > b) --tr;
    while ((tr + 1) * (126 - tr) / 2 <= b) ++tr;
    tc = tr + 1 + (b - tr * (127 - tr) / 2);
  } else {
    tr = tc = b - 2016;
  }
  bool diag = (tr == tc);

  __shared__ alignas(16) unsigned char Ash[TILE * 128];  // 16 KB (one K-half)
  __shared__ alignas(16) unsigned char Bsh[TILE * 128];  // 16 KB
  __shared__ float sqR2[TILE], sqC2[TILE];
  __shared__ double red[4];

  int t = threadIdx.x;
  int wave = t >> 6, lane = t & 63;
  int mrow = lane & 15, q = lane >> 4;
  int wr = (wave & 1) * 64, wc = (wave >> 1) * 64;
  const int sone = 0x7F7F7F7F;  // e8m0 scale = 1.0

  const unsigned char* Ag = X8 + (size_t)tr * TILE * DDIM;
  const unsigned char* Bg = X8 + (size_t)tc * TILE * DDIM;

  // ---- issue half-0 staging FIRST (bw0 compute hides behind it) ----
  #pragma unroll
  for (int cc = 0; cc < 4; ++cc) {
    int c = t + cc * 256;
    int row = c >> 3, kcs = c & 7;
    int kc = kcs ^ (row & 7);
    gl_lds16(Ag + (size_t)row * DDIM + kc * 16, Ash + c * 16);
  }
  if (!diag) {
    #pragma unroll
    for (int cc = 0; cc < 4; ++cc) {
      int c = t + cc * 256;
      int row = c >> 3, kcs = c & 7;
      int kc = kcs ^ (row & 7);
      gl_lds16(Bg + (size_t)row * DDIM + kc * 16, Bsh + c * 16);
    }
  }

  // ---- wave-redundant bw0: colsum^2 sum + ssq, 6 shuffle rounds, no LDS ----
  float4 cv = ((const float4*)colsum)[lane];
  float scp = cv.x * cv.x + cv.y * cv.y + cv.z * cv.z + cv.w * cv.w;
  #pragma unroll
  for (int off = 32; off; off >>= 1) scp += __shfl_down(scp, off);
  scp = __shfl(scp, 0);                 // Σ colsum_d^2 (all lanes)
  float ssq = *ssqacc;
  double sumL2 = 2.0 * 8192.0 * (double)ssq - 2.0 * (double)scp;
  double bw0 = sumL2 / (8192.0 * 8192.0 - 8192.0) / 4.0;
  float kk = (float)(-1.44269504088896 / (16.0 * bw0));  // cs * log2(e)

  if (t < 128) sqR2[t] = kk * sq[tr * TILE + t];
  else         sqC2[t - 128] = kk * sq[tc * TILE + (t - 128)];

  f32x4 acc[4][4];
  #pragma unroll
  for (int i = 0; i < 4; ++i)
    #pragma unroll
    for (int j = 0; j < 4; ++j) acc[i][j] = (f32x4){0.f, 0.f, 0.f, 0.f};

  // ---- two K-halves of 128 bytes, single-buffered ----
  for (int s = 0; s < 2; ++s) {
    if (s) {  // restage half 1
      __syncthreads();  // all reads of half 0 complete
      #pragma unroll
      for (int cc = 0; cc < 4; ++cc) {
        int c = t + cc * 256;
        int row = c >> 3, kcs = c & 7;
        int kc = kcs ^ (row & 7);
        gl_lds16(Ag + (size_t)row * DDIM + 128 + kc * 16, Ash + c * 16);
      }
      if (!diag) {
        #pragma unroll
        for (int cc = 0; cc < 4; ++cc) {
          int c = t + cc * 256;
          int row = c >> 3, kcs = c & 7;
          int kc = kcs ^ (row & 7);
          gl_lds16(Bg + (size_t)row * DDIM + 128 + kc * 16, Bsh + c * 16);
        }
      }
    }
    __syncthreads();  // staging done (s=0: also sqR2/sqC2 visible)

    const unsigned char* Bs = diag ? Ash : Bsh;
    int kc0 = q * 2;
    i32x8 af[4], bf[4];
    #pragma unroll
    for (int f = 0; f < 4; ++f) {
      int rowA = wr + 16 * f + mrow;
      int rowB = wc + 16 * f + mrow;
      int sw = mrow & 7;
      *(i32x4*)&af[f]       = *(const i32x4*)&Ash[rowA * 128 + (kc0 ^ sw) * 16];
      *((i32x4*)&af[f] + 1) = *(const i32x4*)&Ash[rowA * 128 + ((kc0 + 1) ^ sw) * 16];
      *(i32x4*)&bf[f]       = *(const i32x4*)&Bs[rowB * 128 + (kc0 ^ sw) * 16];
      *((i32x4*)&bf[f] + 1) = *(const i32x4*)&Bs[rowB * 128 + ((kc0 + 1) ^ sw) * 16];
    }
    #pragma unroll
    for (int fr = 0; fr < 4; ++fr)
      #pragma unroll
      for (int fc = 0; fc < 4; ++fc)
        acc[fr][fc] = __builtin_amdgcn_mfma_scale_f32_16x16x128_f8f6f4(
            af[fr], bf[fc], acc[fr][fc], 0, 0, 0, sone, 0, sone);
  }

  // epilogue: x = -2k*dot + sr + sc; w = exp2(x); ksum = w+w2+w4+w8+w16.
  // packed f32x2; no clamp (only diag ~0, err negligible).
  // C/D layout col=lane&15, row=(lane>>4)*4+reg [m89/m91; dtype-indep]
  float a2s = -2.f * kk;
  f32x2 a2 = {a2s, a2s};
  f32x2 sum2 = {0.f, 0.f};
  int rq = q * 4, cl = mrow;
  #pragma unroll
  for (int fr = 0; fr < 4; ++fr) {
    int rbase = wr + 16 * fr + rq;
    f32x2 sr01 = {sqR2[rbase + 0], sqR2[rbase + 1]};
    f32x2 sr23 = {sqR2[rbase + 2], sqR2[rbase + 3]};
    #pragma unroll
    for (int fc = 0; fc < 4; ++fc) {
      float sc = sqC2[wc + 16 * fc + cl];
      f32x2 scv = {sc, sc};
      f32x2 d01 = {acc[fr][fc][0], acc[fr][fc][1]};
      f32x2 d23 = {acc[fr][fc][2], acc[fr][fc][3]};
      f32x2 x01 = a2 * d01 + (sr01 + scv);
      f32x2 x23 = a2 * d23 + (sr23 + scv);
      f32x2 w01 = {__builtin_amdgcn_exp2f(x01.x), __builtin_amdgcn_exp2f(x01.y)};
      f32x2 w23 = {__builtin_amdgcn_exp2f(x23.x), __builtin_amdgcn_exp2f(x23.y)};
      f32x2 p01 = w01 * w01, p23 = w23 * w23;           // w^2
      f32x2 s01 = w01 + p01, s23 = w23 + p23;
      p01 = p01 * p01; p23 = p23 * p23;                 // w^4
      s01 = s01 + p01; s23 = s23 + p23;
      p01 = p01 * p01; p23 = p23 * p23;                 // w^8
      s01 = s01 + p01; s23 = s23 + p23;
      p01 = p01 * p01; p23 = p23 * p23;                 // w^16
      s01 = s01 + p01; s23 = s23 + p23;
      sum2 = sum2 + (s01 + s23);
    }
  }
  float lsum = sum2.x + sum2.y;

  double wt = diag ? 1.0 : 2.0;
  if ((tr < 32) != (tc < 32)) wt = -wt;  // s_i*s_j uniform per 128-tile
  double ds = (double)lsum * wt;
  #pragma unroll
  for (int off = 32; off; off >>= 1) ds += __shfl_down(ds, off);
  if (lane == 0) red[wave] = ds;
  __syncthreads();
  if (t == 0) Spart[b] = red[0] + red[1] + red[2] + red[3];
}

// ---- final reduce of 2080 per-block partials ----
__global__ __launch_bounds__(256) void kfin(const double* __restrict__ Spart,
                                            float* __restrict__ out) {
  int t = threadIdx.x;
  double s = 0.0;
  #pragma unroll
  for (int i = 0; i < 9; ++i) {
    int idx = t + i * 256;
    if (idx < NBLK) s += Spart[idx];
  }
  __shared__ double red[256];
  red[t] = s;
  __syncthreads();
  for (int off = 128; off; off >>= 1) {
    if (t < off) red[t] += red[t + off];
    __syncthreads();
  }
  if (t == 0) out[0] = (float)(red[0] / (4096.0 * 4096.0));
}

extern "C" void kernel_launch(void* const* d_in, const int* in_sizes, int n_in,
                              void* d_out, int out_size, void* d_ws, size_t ws_size,
                              hipStream_t stream) {
  const float* src = (const float*)d_in[0];
  const float* tgt = (const float*)d_in[1];
  char* ws = (char*)d_ws;
  unsigned char* X8 = (unsigned char*)ws;             // 8192*256 = 2 MiB
  float* sq      = (float*)(ws + 2097152);            // 32 KiB
  float* colsum  = (float*)(ws + 2129920);            // 256 f + 1 f (ssq)
  float* ssqacc  = colsum + 256;
  double* Spart  = (double*)(ws + 2131968);           // 16.25 KiB
  float* out = (float*)d_out;

  hipMemsetAsync((void*)colsum, 0, 1040, stream);     // zero atomic targets
  hipLaunchKernelGGL(kconv, dim3(256), dim3(256), 0, stream,
                     src, tgt, X8, sq, colsum, ssqacc);
  hipLaunchKernelGGL(kgemm, dim3(NBLK), dim3(256), 0, stream,
                     X8, sq, colsum, ssqacc, Spart);
  hipLaunchKernelGGL(kfin, dim3(1), dim3(256), 0, stream, Spart, out);
}